// Round 5
// baseline (599.225 us; speedup 1.0000x reference)
//
#include <hip/hip_runtime.h>
#include <math.h>

// Math reduction (EPS=1e-12 negligible for x ~ N(0,1)):
//   gain_j = logit x_j exactly; base = sum_j softplus(x_j);
//   pos = sum_{m=1, x>0} x ; best = max_{m=1} x
//   per_sample = base - (pos>0 ? pos : best);  answer = mean over rows.
//
// Round-5 experiment: identical structure to round 4 (one 256-thread block
// per row) but the global reads go through the async global->LDS DMA path
// (__builtin_amdgcn_global_load_lds, width=16) instead of VGPR-return loads.
// Rounds 1-4 all pinned at 2.65 TB/s (~4.3 B/cyc/CU = L1 miss-queue
// signature) regardless of occupancy / load depth / block lifetime; the DMA
// path is the one request mechanism not yet tested. Finalize kernel replaced
// by zero_out + one float atomicAdd per block.

constexpr int B = 32768;
constexpr int C = 1000;
constexpr int C4 = C / 4;           // 250 float4 per row
constexpr int THREADS = 256;

typedef float GF __attribute__((address_space(1)));   // global
typedef float LF __attribute__((address_space(3)));   // LDS

__device__ __forceinline__ void elem_update(float x, float m,
                                            float& base, float& pos, float& best) {
    // softplus(x) = max(x,0) + log(1 + exp(-|x|))
    float e  = __expf(-fabsf(x));
    float xp = fmaxf(x, 0.0f);
    base += xp + __logf(1.0f + e);
    pos  += m * xp;                       // m in {0,1}
    if (m != 0.0f) best = fmaxf(best, x);
}

__global__ void zero_out(float* __restrict__ out) {
    if (threadIdx.x == 0) out[0] = 0.0f;
}

__global__ __launch_bounds__(THREADS)
void row_loss_kernel(const float* __restrict__ X,
                     const float* __restrict__ M,
                     float* __restrict__ out) {
    __shared__ float4 ldsX[256];   // 4096 B (row uses 4000; tail slack)
    __shared__ float4 ldsM[256];

    const int row  = blockIdx.x;
    const int t    = threadIdx.x;
    const int w    = t >> 6;       // wave id 0..3
    const int lane = t & 63;

    const float* xrow = X + (size_t)row * C;
    const float* mrow = M + (size_t)row * C;

    // Wave w stages chunk w of each array: bytes [1024w, 1024w+1024)
    // (chunk 3 covers only 928 B -> lanes 58..63 masked off; LDS dest is
    //  wave-uniform base + lane*16, global addr is per-lane).
    {
        const float* gx = xrow + w * 256 + lane * 4;
        const float* gm = mrow + w * 256 + lane * 4;
        LF* lx = (LF*)((float*)ldsX + w * 256);
        LF* lm = (LF*)((float*)ldsM + w * 256);
        if (w < 3 || lane < 58) {
            __builtin_amdgcn_global_load_lds((const GF*)gx, lx, 16, 0, 0);
            __builtin_amdgcn_global_load_lds((const GF*)gm, lm, 16, 0, 0);
        }
    }
    __syncthreads();   // drains vmcnt -> DMA complete

    float base = 0.f, pos = 0.f, best = -INFINITY;
    if (t < C4) {
        float4 x = ldsX[t];
        float4 m = ldsM[t];
        elem_update(x.x, m.x, base, pos, best);
        elem_update(x.y, m.y, base, pos, best);
        elem_update(x.z, m.z, base, pos, best);
        elem_update(x.w, m.w, base, pos, best);
    }

    // wave-level reduction (64 lanes)
    #pragma unroll
    for (int off = 32; off > 0; off >>= 1) {
        base += __shfl_down(base, off, 64);
        pos  += __shfl_down(pos,  off, 64);
        best  = fmaxf(best, __shfl_down(best, off, 64));
    }

    __shared__ float sb[4], sp[4], ss[4];
    if (lane == 0) { sb[w] = base; sp[w] = pos; ss[w] = best; }
    __syncthreads();
    if (t == 0) {
        float b = (sb[0] + sb[1]) + (sb[2] + sb[3]);
        float p = (sp[0] + sp[1]) + (sp[2] + sp[3]);
        float s = fmaxf(fmaxf(ss[0], ss[1]), fmaxf(ss[2], ss[3]));
        float per = b - ((p > 0.f) ? p : s);
        atomicAdd(out, per * (1.0f / (float)B));
    }
}

extern "C" void kernel_launch(void* const* d_in, const int* in_sizes, int n_in,
                              void* d_out, int out_size, void* d_ws, size_t ws_size,
                              hipStream_t stream) {
    const float* X = (const float*)d_in[0];
    const float* M = (const float*)d_in[1];
    float* out     = (float*)d_out;

    zero_out<<<1, 64, 0, stream>>>(out);
    row_loss_kernel<<<B, THREADS, 0, stream>>>(X, M, out);
}

// Round 6
// 245.939 us; speedup vs baseline: 2.4365x; 2.4365x over previous
//
#include <hip/hip_runtime.h>
#include <math.h>

// Math reduction (EPS=1e-12 negligible for x ~ N(0,1)):
//   gain_j = logit x_j exactly; base = sum_j softplus(x_j);
//   pos = sum_{m=1, x>0} x ; best = max_{m=1} x
//   per_sample = base - (pos>0 ? pos : best);  answer = mean over rows.
//
// Round-6 experiment: round-4 structure (one 256-thread block per row; best
// measured at 99.3 us) with NON-TEMPORAL loads (nt bit -> L1 bypass).
// Rounds 1-4 pinned at 2.65 TB/s = 1 line/30cyc/CU regardless of occupancy/
// ILP/block lifetime and regardless of HBM-cold vs L3-warm -> per-miss L1
// allocation serialization is the suspected wall; nt loads skip L1 allocate.
// Finalize: 2-stage deterministic tree (no atomics, no single-block 32K scan).

constexpr int B = 32768;
constexpr int C = 1000;
constexpr int C4 = C / 4;       // 250 float4 per row; threads 250..255 idle
constexpr int THREADS = 256;

typedef float f32x4 __attribute__((ext_vector_type(4)));

__device__ __forceinline__ void elem_update(float x, float m,
                                            float& base, float& pos, float& best) {
    // softplus(x) = max(x,0) + log(1 + exp(-|x|))
    float e  = __expf(-fabsf(x));
    float xp = fmaxf(x, 0.0f);
    base += xp + __logf(1.0f + e);
    pos  += m * xp;                       // m in {0,1}; only x>0 contributes
    if (m != 0.0f) best = fmaxf(best, x);
}

__global__ __launch_bounds__(THREADS)
void row_loss_kernel(const float* __restrict__ X,
                     const float* __restrict__ M,
                     float* __restrict__ partial) {
    const int row = blockIdx.x;
    const int t   = threadIdx.x;

    float base = 0.f, pos = 0.f, best = -INFINITY;

    if (t < C4) {
        const f32x4* x4 = reinterpret_cast<const f32x4*>(X + (size_t)row * C);
        const f32x4* m4 = reinterpret_cast<const f32x4*>(M + (size_t)row * C);
        f32x4 x = __builtin_nontemporal_load(x4 + t);   // nt: bypass L1 allocate
        f32x4 m = __builtin_nontemporal_load(m4 + t);
        elem_update(x.x, m.x, base, pos, best);
        elem_update(x.y, m.y, base, pos, best);
        elem_update(x.z, m.z, base, pos, best);
        elem_update(x.w, m.w, base, pos, best);
    }

    // wave-level reduction (64 lanes)
    #pragma unroll
    for (int off = 32; off > 0; off >>= 1) {
        base += __shfl_down(base, off, 64);
        pos  += __shfl_down(pos,  off, 64);
        best  = fmaxf(best, __shfl_down(best, off, 64));
    }

    __shared__ float sb[4], sp[4], ss[4];
    const int w    = t >> 6;
    const int lane = t & 63;
    if (lane == 0) { sb[w] = base; sp[w] = pos; ss[w] = best; }
    __syncthreads();
    if (t == 0) {
        float b = (sb[0] + sb[1]) + (sb[2] + sb[3]);
        float p = (sp[0] + sp[1]) + (sp[2] + sp[3]);
        float s = fmaxf(fmaxf(ss[0], ss[1]), fmaxf(ss[2], ss[3]));
        partial[row] = b - ((p > 0.f) ? p : s);
    }
}

// Stage 1: 64 blocks x 256 threads; block b reduces partial[512b .. 512b+511]
__global__ __launch_bounds__(256)
void finalize1_kernel(const float* __restrict__ partial, float* __restrict__ mid) {
    const int b = blockIdx.x;
    const int t = threadIdx.x;
    float v = partial[b * 512 + t] + partial[b * 512 + t + 256];

    #pragma unroll
    for (int off = 32; off > 0; off >>= 1)
        v += __shfl_down(v, off, 64);

    __shared__ float s[4];
    const int w    = t >> 6;
    const int lane = t & 63;
    if (lane == 0) s[w] = v;
    __syncthreads();
    if (t == 0) mid[b] = (s[0] + s[1]) + (s[2] + s[3]);
}

// Stage 2: 1 block x 64 threads; double-precision sum of 64 values, mean.
__global__ __launch_bounds__(64)
void finalize2_kernel(const float* __restrict__ mid, float* __restrict__ out) {
    double v = (double)mid[threadIdx.x];
    #pragma unroll
    for (int off = 32; off > 0; off >>= 1)
        v += __shfl_down(v, off, 64);
    if (threadIdx.x == 0) out[0] = (float)(v / (double)B);
}

extern "C" void kernel_launch(void* const* d_in, const int* in_sizes, int n_in,
                              void* d_out, int out_size, void* d_ws, size_t ws_size,
                              hipStream_t stream) {
    const float* X  = (const float*)d_in[0];
    const float* M  = (const float*)d_in[1];
    float* out      = (float*)d_out;
    float* partial  = (float*)d_ws;          // 32768 floats
    float* mid      = partial + B;           // 64 floats

    row_loss_kernel<<<B, THREADS, 0, stream>>>(X, M, partial);
    finalize1_kernel<<<64, 256, 0, stream>>>(partial, mid);
    finalize2_kernel<<<1, 64, 0, stream>>>(mid, out);
}